// Round 10
// baseline (118.651 us; speedup 1.0000x reference)
//
#include <hip/hip_runtime.h>

typedef float v2f __attribute__((ext_vector_type(2)));
typedef _Float16 h2f __attribute__((ext_vector_type(2)));

namespace {

constexpr int Tn = 1000, Fn = 22, Hn = 10, Cn = 4;
constexpr int CHF = 32 * Fn;      // 704 floats per 32-step x chunk
constexpr int XZ  = 2 * CHF;      // x zone: floats [0, 1408)
constexpr int RZ  = XZ;           // h1 ring: [1408, 1920) = 2 slots x 32 entries x 8 floats
constexpr int DZ  = XZ + 512;     // dump: [1920, 2496)
constexpr int LDSF = DZ + 576;

__device__ __forceinline__ v2f mk2(float a, float b){ v2f r; r.x=a; r.y=b; return r; }
__device__ __forceinline__ v2f fma2(v2f a, v2f b, v2f c){ return __builtin_elementwise_fma(a,b,c); }
__device__ __forceinline__ unsigned rlaneu(unsigned v, int l){
    return (unsigned)__builtin_amdgcn_readlane((int)v, l);
}
__device__ __forceinline__ void gld_lds4(const float* g, float* l){
    __builtin_amdgcn_global_load_lds(
        (const __attribute__((address_space(1))) unsigned int*)g,
        (__attribute__((address_space(3))) unsigned int*)l, 4, 0, 0);
}
__device__ __forceinline__ void sfence(){ __builtin_amdgcn_sched_barrier(0); }
__device__ __forceinline__ void lgkm0_bar(){
    asm volatile("s_waitcnt lgkmcnt(0)" ::: "memory");
    __builtin_amdgcn_s_barrier();
}
__device__ __forceinline__ h2f u2h(unsigned u){ return __builtin_bit_cast(h2f, u); }
__device__ __forceinline__ unsigned packpair(float hn){
    const float nb = __uint_as_float((unsigned)__builtin_amdgcn_mov_dpp(
                         (int)__float_as_uint(hn), 0xB1, 0xF, 0xF, false));
    return __builtin_bit_cast(unsigned, __builtin_amdgcn_cvt_pkrtz(hn, nb));
}

__global__ __launch_bounds__(128, 2) void rnn_lag(
    const float* __restrict__ x,
    const float* __restrict__ w_ih0, const float* __restrict__ w_hh0,
    const float* __restrict__ b_ih0, const float* __restrict__ b_hh0,
    const float* __restrict__ w_ih1, const float* __restrict__ w_hh1,
    const float* __restrict__ b_ih1, const float* __restrict__ b_hh1,
    const float* __restrict__ w_lin, const float* __restrict__ b_lin,
    float* __restrict__ out)
{
    __shared__ __align__(16) float lds[LDSF];

    const int tid  = threadIdx.x;
    const int wid  = tid >> 6;          // wave 0: L1 producer, wave 1: L2 consumer
    const int lane = tid & 63;
    const int b    = blockIdx.x;
    const float* __restrict__ xrow = x + (size_t)b * (Tn * Fn);

    if (wid == 0) {
        // ========================= WAVE A: layer-1 =========================
        const int half = lane >> 5;              // 0: even steps, 1: odd steps
        const int l31  = lane & 31;
        const int jz   = (l31 < Hn) ? l31 : 0;

        h2f waH[5];
        #pragma unroll
        for (int k = 0; k < 5; ++k) {
            h2f t; t.x = (_Float16)w_hh0[jz*Hn + 2*k];
                   t.y = (_Float16)w_hh0[jz*Hn + 2*k + 1];
            waH[k] = t;
        }
        v2f wih0p[11];
        #pragma unroll
        for (int p = 0; p < 11; ++p)
            wih0p[p] = mk2(w_ih0[jz*Fn + 2*p], w_ih0[jz*Fn + 2*p + 1]);
        const v2f bz2 = mk2(b_ih0[jz] + b_hh0[jz], 0.f);

        // ring write indices (pk pairs live on even lanes; others -> dump)
        const bool vE = (lane < 10) && !(lane & 1);
        const bool vO = (lane >= 32) && (lane < 42) && !(lane & 1);
        const int wEi = vE ? RZ + (lane >> 1)        : DZ + lane;
        const int wOi = vO ? RZ + ((lane - 32) >> 1) : DZ + lane;

        auto stage = [&](int c) {                 // x chunk c -> x slot c&1
            float* dst = lds + (c & 1) * CHF;
            const float* src = xrow + c * CHF;
            if (c < 31) {
                #pragma unroll
                for (int k = 0; k < 11; ++k) gld_lds4(src + k*64 + lane, dst + k*64);
            } else {
                gld_lds4(src + lane, dst);
                gld_lds4(src + 64 + lane, dst + 64);
                if (lane < 48) gld_lds4(src + 128 + lane, dst + 128);
            }
        };
        stage(0); stage(1);

        v2f xd[11], xv0[11], xv1[11];
        {
            const float* r01 = xrow + half * Fn;
            #pragma unroll
            for (int p = 0; p < 11; ++p) xd[p] = *(const v2f*)(r01 + 2*p);
            const float* r23 = xrow + (2 + half) * Fn;
            #pragma unroll
            for (int p = 0; p < 11; ++p) xv0[p] = *(const v2f*)(r23 + 2*p);
        }
        auto zc = [&](const v2f* xp) -> float {
            v2f z = fma2(xp[0], wih0p[0], bz2);
            #pragma unroll
            for (int p = 1; p < 11; ++p) z = fma2(xp[p], wih0p[p], z);
            return z.x + z.y;
        };
        auto loadxv = [&](v2f* dst, const float* rp) {
            #pragma unroll
            for (int p = 0; p < 11; ++p) dst[p] = *(const v2f*)(rp + 2*p);
            sfence();
        };

        unsigned S1u[5];
        #pragma unroll
        for (int k = 0; k < 5; ++k) S1u[k] = 0u;

        asm volatile("s_waitcnt vmcnt(0)" ::: "memory");
        float zA = zc(xd), zB;

        auto stepA = [&](float z, int rbase, float* wp, int stoff) {
            float c0 = __builtin_amdgcn_fdot2(u2h(S1u[0]), waH[0], z, false);
            c0 = __builtin_amdgcn_fdot2(u2h(S1u[1]), waH[1], c0, false);
            c0 = __builtin_amdgcn_fdot2(u2h(S1u[2]), waH[2], c0, false);
            float c1 = __builtin_amdgcn_fdot2(u2h(S1u[3]), waH[3], 0.f, false);
            c1 = __builtin_amdgcn_fdot2(u2h(S1u[4]), waH[4], c1, false);
            const float hn = fmaxf(c0 + c1, 0.f);
            const unsigned pk = packpair(hn);
            #pragma unroll
            for (int k = 0; k < 5; ++k) S1u[k] = rlaneu(pk, rbase + 2*k);
            wp[stoff] = __uint_as_float(pk);           // ds_write_b32, imm offset
        };
        // 4 steps; l0/l1: x pair pointers (null = skip); st: entry base (literal)
        auto MACRO = [&](const float* l0, const float* l1,
                         float* wE, float* wO, int st, bool z1) {
            if (l0) loadxv(xv1, l0);
            stepA(zA, 0,  wE, (st + 0) * 8);
            zB = zc(xv0);
            stepA(zA, 32, wO, (st + 1) * 8);
            if (l1) loadxv(xv0, l1);
            stepA(zB, 0,  wE, (st + 2) * 8);
            if (z1) zA = zc(xv1);
            stepA(zB, 32, wO, (st + 3) * 8);
        };

        #pragma unroll 1
        for (int s = 0; s <= 32; ++s) {
            if (s < 32) {
                const int sh = (s & 1) * 256;
                float* wE = lds + wEi + sh;
                float* wO = lds + wOi + sh;
                const float* xbt = lds + (s & 1) * CHF + half * 22;        // chunk s
                const float* xbn = lds + ((s + 1) & 1) * CHF + half * 22;  // chunk s+1
                if (s < 31) {
                    #pragma unroll
                    for (int mm = 0; mm < 7; ++mm)
                        MACRO(xbt + (2*mm + 2) * 44, xbt + (2*mm + 3) * 44,
                              wE, wO, mm * 4, true);
                    asm volatile("s_waitcnt vmcnt(0)" ::: "memory");
                    if (s + 2 <= 31) stage(s + 2);
                    MACRO(xbn, xbn + 44, wE, wO, 28, true);   // pairs 0,1 of chunk s+1
                } else {  // segment 31: steps 992..999 only
                    MACRO(xbt + 2*44, xbt + 3*44, wE, wO, 0, true);
                    MACRO(nullptr, nullptr, wE, wO, 4, false);
                }
            }
            lgkm0_bar();
        }
    } else {
        // ========================= WAVE B: layer-2 + head =========================
        const int j2 = (lane < Hn) ? lane : 0;
        h2f wih1H[5], whh1H[5], wlinH[5];
        const int jc = (lane < Cn) ? lane : 0;
        #pragma unroll
        for (int k = 0; k < 5; ++k) {
            h2f t; t.x = (_Float16)w_ih1[j2*Hn + 2*k];
                   t.y = (_Float16)w_ih1[j2*Hn + 2*k + 1];
            wih1H[k] = t;
            h2f u; u.x = (_Float16)w_hh1[j2*Hn + 2*k];
                   u.y = (_Float16)w_hh1[j2*Hn + 2*k + 1];
            whh1H[k] = u;
            h2f w; w.x = (_Float16)w_lin[jc*Hn + 2*k];
                   w.y = (_Float16)w_lin[jc*Hn + 2*k + 1];
            wlinH[k] = w;
        }
        const float b2v = b_ih1[j2] + b_hh1[j2];
        const float blv = b_lin[jc];

        unsigned S2u[5];
        #pragma unroll
        for (int k = 0; k < 5; ++k) S2u[k] = 0u;

        auto stepB = [&](uint4 q, unsigned q4) {
            float d0 = __builtin_amdgcn_fdot2(u2h(q.x), wih1H[0], b2v, false);
            d0 = __builtin_amdgcn_fdot2(u2h(q.y), wih1H[1], d0, false);
            d0 = __builtin_amdgcn_fdot2(u2h(q.z), wih1H[2], d0, false);
            float d1 = __builtin_amdgcn_fdot2(u2h(q.w), wih1H[3], 0.f, false);
            d1 = __builtin_amdgcn_fdot2(u2h(q4),  wih1H[4], d1, false);
            d0 = __builtin_amdgcn_fdot2(u2h(S2u[0]), whh1H[0], d0, false);
            d1 = __builtin_amdgcn_fdot2(u2h(S2u[1]), whh1H[1], d1, false);
            d0 = __builtin_amdgcn_fdot2(u2h(S2u[2]), whh1H[2], d0, false);
            d1 = __builtin_amdgcn_fdot2(u2h(S2u[3]), whh1H[3], d1, false);
            d0 = __builtin_amdgcn_fdot2(u2h(S2u[4]), whh1H[4], d0, false);
            const float hn = fmaxf(d0 + d1, 0.f);
            const unsigned pk = packpair(hn);
            #pragma unroll
            for (int k = 0; k < 5; ++k) S2u[k] = rlaneu(pk, 2*k);
        };

        #pragma unroll 1
        for (int s = 0; s <= 32; ++s) {
            if (s >= 1) {
                const float* rb = lds + RZ + ((s - 1) & 1) * 256;
                uint4 qa = *(const uint4*)(rb + 0);
                unsigned ra = *(const unsigned*)(rb + 4);
                uint4 qb = *(const uint4*)(rb + 8);
                unsigned rbx = *(const unsigned*)(rb + 12);
                sfence();
                if (s - 1 < 31) {
                    #pragma unroll
                    for (int st = 0; st < 32; st += 2) {
                        uint4 ca = qa; unsigned c4a = ra;
                        if (st + 2 < 32) { qa = *(const uint4*)(rb + (st+2)*8);
                                           ra = *(const unsigned*)(rb + (st+2)*8 + 4); }
                        stepB(ca, c4a);
                        uint4 cb = qb; unsigned c4b = rbx;
                        if (st + 3 < 32) { qb = *(const uint4*)(rb + (st+3)*8);
                                           rbx = *(const unsigned*)(rb + (st+3)*8 + 4); }
                        stepB(cb, c4b);
                    }
                } else {  // last segment: 8 steps
                    #pragma unroll
                    for (int st = 0; st < 8; st += 2) {
                        uint4 ca = qa; unsigned c4a = ra;
                        if (st + 2 < 8) { qa = *(const uint4*)(rb + (st+2)*8);
                                          ra = *(const unsigned*)(rb + (st+2)*8 + 4); }
                        stepB(ca, c4a);
                        uint4 cb = qb; unsigned c4b = rbx;
                        if (st + 3 < 8) { qb = *(const uint4*)(rb + (st+3)*8);
                                          rbx = *(const unsigned*)(rb + (st+3)*8 + 4); }
                        stepB(cb, c4b);
                    }
                }
            }
            lgkm0_bar();
        }

        // head: out[b,:] = h2(999) @ w_lin.T + b_lin
        float o = blv;
        #pragma unroll
        for (int k = 0; k < 5; ++k)
            o = __builtin_amdgcn_fdot2(u2h(S2u[k]), wlinH[k], o, false);
        if (lane < Cn) out[b * Cn + lane] = o;
    }
}

} // namespace

extern "C" void kernel_launch(void* const* d_in, const int* in_sizes, int n_in,
                              void* d_out, int out_size, void* d_ws, size_t ws_size,
                              hipStream_t stream) {
    const float* x     = (const float*)d_in[0];
    const float* w_ih0 = (const float*)d_in[1];
    const float* w_hh0 = (const float*)d_in[2];
    const float* b_ih0 = (const float*)d_in[3];
    const float* b_hh0 = (const float*)d_in[4];
    const float* w_ih1 = (const float*)d_in[5];
    const float* w_hh1 = (const float*)d_in[6];
    const float* b_ih1 = (const float*)d_in[7];
    const float* b_hh1 = (const float*)d_in[8];
    const float* w_lin = (const float*)d_in[9];
    const float* b_lin = (const float*)d_in[10];
    float* out = (float*)d_out;

    // one batch per 128-thread block (wave A: L1, wave B: L2, one segment lag)
    // 1024 blocks x 2 waves = 2048 waves -> 2 co-resident waves per SIMD
    rnn_lag<<<dim3(1024), dim3(128), 0, stream>>>(
        x, w_ih0, w_hh0, b_ih0, b_hh0,
        w_ih1, w_hh1, b_ih1, b_hh1, w_lin, b_lin, out);
}

// Round 11
// 103.246 us; speedup vs baseline: 1.1492x; 1.1492x over previous
//
#include <hip/hip_runtime.h>

typedef float v2f __attribute__((ext_vector_type(2)));
typedef _Float16 h2f __attribute__((ext_vector_type(2)));

namespace {

constexpr int Tn = 1000, Fn = 22, Hn = 10, Cn = 4;

__device__ __forceinline__ v2f mk2(float a, float b){ v2f r; r.x=a; r.y=b; return r; }
__device__ __forceinline__ v2f fma2(v2f a, v2f b, v2f c){ return __builtin_elementwise_fma(a,b,c); }
__device__ __forceinline__ unsigned rlaneu(unsigned v, int l){
    return (unsigned)__builtin_amdgcn_readlane((int)v, l);
}
__device__ __forceinline__ h2f u2h(unsigned u){ return __builtin_bit_cast(h2f, u); }
__device__ __forceinline__ void sfence(){ __builtin_amdgcn_sched_barrier(0); }

__global__ __launch_bounds__(64, 1) void rnn_zpre(
    const float* __restrict__ x,
    const float* __restrict__ w_ih0, const float* __restrict__ w_hh0,
    const float* __restrict__ b_ih0, const float* __restrict__ b_hh0,
    const float* __restrict__ w_ih1, const float* __restrict__ w_hh1,
    const float* __restrict__ b_ih1, const float* __restrict__ b_hh1,
    const float* __restrict__ w_lin, const float* __restrict__ b_lin,
    float* __restrict__ out)
{
    // z[t][j] for t=0..999 (rows 1000+ zeroed; L2 lanes read the zero zone)
    __shared__ float zl[10240];   // 40960 B -> exactly 4 blocks/CU

    const int lane = threadIdx.x;            // one wave per block, one batch
    const int b    = blockIdx.x;
    const float* __restrict__ xb = x + (size_t)b * (Tn * Fn);

    // ============ phase 1: z = bias1 + x @ w_ih0^T  (into LDS) ============
    {
        const int g = lane / 10;             // 0..6
        const int j = lane - 10 * g;         // 0..9
        v2f wih[11];
        #pragma unroll
        for (int p = 0; p < 11; ++p) wih[p] = *(const v2f*)(w_ih0 + j*Fn + 2*p);
        const float b1 = b_ih0[j] + b_hh0[j];

        v2f xr[5][11];                       // 5-deep prefetch ring
        auto ldx = [&](v2f* d, int trow){
            const float* s = xb + trow * Fn;
            #pragma unroll
            for (int p = 0; p < 11; ++p) d[p] = *(const v2f*)(s + 2*p);
        };
        auto dotz = [&](const v2f* v)->float{
            v2f a = fma2(v[0], wih[0], mk2(b1, 0.f));
            #pragma unroll
            for (int p = 1; p < 11; ++p) a = fma2(v[p], wih[p], a);
            return a.x + a.y;
        };
        #pragma unroll
        for (int s = 0; s < 5; ++s) ldx(xr[s], g + 6*s);

        auto body = [&](int i, v2f* slot){
            const float z = dotz(slot);
            const int zi = lane + 60 * i;    // == (g+6i)*10 + j
            if (zi < 10000) zl[zi] = z;
            int tr = g + 6*i + 30;           // refill for iteration i+5
            tr = (tr > 999) ? 999 : tr;
            ldx(slot, tr);
        };
        #pragma unroll 1
        for (int i = 0; i < 165; i += 5) {
            body(i,   xr[0]); body(i+1, xr[1]); body(i+2, xr[2]);
            body(i+3, xr[3]); body(i+4, xr[4]);
        }
        { const float z = dotz(xr[0]); const int zi = lane + 60*165; if (zi < 10000) zl[zi] = z; }
        { const float z = dotz(xr[1]); const int zi = lane + 60*166; if (zi < 10000) zl[zi] = z; }

        // zero rows 1000.. (indices 10000..10239)
        #pragma unroll
        for (int k = 0; k < 4; ++k) {
            const int idx = 10000 + lane + 64*k;
            if (idx < 10240) zl[idx] = 0.f;
        }
    }
    asm volatile("s_waitcnt lgkmcnt(0)" ::: "memory");   // z fully visible (same wave)

    // ============ phase 2: pure recurrence (minimal chain) ============
    const int jz   = (lane < Hn) ? lane : 0;
    const bool isl2 = (lane >= 16) && (lane < 16 + Hn);
    const int j2   = isl2 ? (lane - 16) : 0;

    const float* pwa = (lane < 16) ? (w_hh0 + jz*Hn) : (w_ih1 + j2*Hn);
    h2f waH[5], wbH[5];
    #pragma unroll
    for (int k = 0; k < 5; ++k) {
        h2f t; t.x = (_Float16)pwa[2*k]; t.y = (_Float16)pwa[2*k+1];
        waH[k] = t;
        h2f u; u.x = isl2 ? (_Float16)w_hh1[j2*Hn + 2*k]     : (_Float16)0.f;
               u.y = isl2 ? (_Float16)w_hh1[j2*Hn + 2*k + 1] : (_Float16)0.f;
        wbH[k] = u;
    }
    const float b2v = isl2 ? (b_ih1[j2] + b_hh1[j2]) : 0.f;

    unsigned S1u[5], S2u[5];
    #pragma unroll
    for (int k = 0; k < 5; ++k) { S1u[k] = 0u; S2u[k] = 0u; }

    // z feed: L1 lanes walk column j starting at row 1; others parked on zeros
    const float* zp = zl + ((lane < Hn) ? (10 + lane) : 10000);
    const int zinc  = (lane < Hn) ? 160 : 0;   // 16 rows per 16-step pair

    // one step: L1(t) lanes 0-9, L2(t-1) lanes 16-25 (uniform stream).
    // 4 accumulator chains (depth<=3); dpp runs parallel to max(s,0).
    auto stepc = [&](float zc, bool c2) {
        float c0 = __builtin_amdgcn_fdot2(u2h(S1u[0]), waH[0], zc, false);
        c0 = __builtin_amdgcn_fdot2(u2h(S1u[1]), waH[1], c0, false);
        c0 = __builtin_amdgcn_fdot2(u2h(S1u[2]), waH[2], c0, false);
        float c1 = __builtin_amdgcn_fdot2(u2h(S1u[3]), waH[3], 0.f, false);
        c1 = __builtin_amdgcn_fdot2(u2h(S1u[4]), waH[4], c1, false);
        float c2a = __builtin_amdgcn_fdot2(u2h(S2u[0]), wbH[0], b2v, false);
        c2a = __builtin_amdgcn_fdot2(u2h(S2u[1]), wbH[1], c2a, false);
        c2a = __builtin_amdgcn_fdot2(u2h(S2u[2]), wbH[2], c2a, false);
        float c3 = __builtin_amdgcn_fdot2(u2h(S2u[3]), wbH[3], 0.f, false);
        c3 = __builtin_amdgcn_fdot2(u2h(S2u[4]), wbH[4], c3, false);
        const float s = (c0 + c1) + (c2a + c3);
        const float sw = __uint_as_float((unsigned)__builtin_amdgcn_mov_dpp(
                             (int)__float_as_uint(s), 0xB1, 0xF, 0xF, false));
        const float lo = fmaxf(s, 0.f);
        const float hi = fmaxf(sw, 0.f);
        const unsigned pk = __builtin_bit_cast(unsigned,
                             __builtin_amdgcn_cvt_pkrtz(lo, hi));
        S1u[0] = rlaneu(pk, 0);  S1u[1] = rlaneu(pk, 2);
        S1u[2] = rlaneu(pk, 4);  S1u[3] = rlaneu(pk, 6);
        S1u[4] = rlaneu(pk, 8);
        if (c2) {
            S2u[0] = rlaneu(pk, 16); S2u[1] = rlaneu(pk, 18);
            S2u[2] = rlaneu(pk, 20); S2u[3] = rlaneu(pk, 22);
            S2u[4] = rlaneu(pk, 24);
        }
    };

    // step 0: commits S1 = h1(0) only (h2(-1) stays 0)
    { const float z0 = zl[(lane < Hn) ? lane : 10000]; stepc(z0, false); }

    float za[8], zb[8];
    #pragma unroll
    for (int s = 0; s < 8; ++s) za[s] = zp[10*s];      // rows 1..8

    #pragma unroll 1
    for (int it = 0; it < 62; ++it) {
        #pragma unroll
        for (int s = 0; s < 8; ++s) zb[s] = zp[80 + 10*s];   // next 8 rows
        sfence();
        #pragma unroll
        for (int s = 0; s < 8; ++s) stepc(za[s], true);
        #pragma unroll
        for (int s = 0; s < 8; ++s) za[s] = zp[160 + 10*s];
        sfence();
        #pragma unroll
        for (int s = 0; s < 8; ++s) stepc(zb[s], true);
        zp += zinc;
    }
    // final 8 steps: 993..1000 (step 1000 uses z=0, commits S2 = h2(999))
    #pragma unroll
    for (int s = 0; s < 8; ++s) stepc(za[s], true);

    // ---- head: out[b,:] = h2(999) @ w_lin.T + b_lin ----
    const int jc = (lane < Cn) ? lane : 0;
    h2f wlinH[5];
    #pragma unroll
    for (int k = 0; k < 5; ++k) {
        h2f w; w.x = (_Float16)w_lin[jc*Hn + 2*k]; w.y = (_Float16)w_lin[jc*Hn + 2*k + 1];
        wlinH[k] = w;
    }
    float o = b_lin[jc];
    #pragma unroll
    for (int k = 0; k < 5; ++k)
        o = __builtin_amdgcn_fdot2(u2h(S2u[k]), wlinH[k], o, false);
    if (lane < Cn) out[b * Cn + lane] = o;
}

} // namespace

extern "C" void kernel_launch(void* const* d_in, const int* in_sizes, int n_in,
                              void* d_out, int out_size, void* d_ws, size_t ws_size,
                              hipStream_t stream) {
    const float* x     = (const float*)d_in[0];
    const float* w_ih0 = (const float*)d_in[1];
    const float* w_hh0 = (const float*)d_in[2];
    const float* b_ih0 = (const float*)d_in[3];
    const float* b_hh0 = (const float*)d_in[4];
    const float* w_ih1 = (const float*)d_in[5];
    const float* w_hh1 = (const float*)d_in[6];
    const float* b_ih1 = (const float*)d_in[7];
    const float* b_hh1 = (const float*)d_in[8];
    const float* w_lin = (const float*)d_in[9];
    const float* b_lin = (const float*)d_in[10];
    float* out = (float*)d_out;

    // one batch per 64-thread block: 1024 waves, 1 per SIMD (LDS-capped 4/CU)
    rnn_zpre<<<dim3(1024), dim3(64), 0, stream>>>(
        x, w_ih0, w_hh0, b_ih0, b_hh0,
        w_ih1, w_hh1, b_ih1, b_hh1, w_lin, b_lin, out);
}